// Round 1
// baseline (244.036 us; speedup 1.0000x reference)
//
#include <hip/hip_runtime.h>
#include <hip/hip_bf16.h>
#include <stdint.h>

// Problem constants
#define B_  2
#define S_  2048
#define D_  1024
#define H_  16
#define DH_ 64

typedef __attribute__((ext_vector_type(8))) short  bf16x8;
typedef __attribute__((ext_vector_type(4))) float  f32x4;

__device__ __forceinline__ unsigned short f2bf(float f) {
    unsigned u = __float_as_uint(f);
    u += 0x7FFF + ((u >> 16) & 1);            // RNE
    return (unsigned short)(u >> 16);
}

__device__ __forceinline__ void gload16(const void* g, void* l) {
    __builtin_amdgcn_global_load_lds(
        (__attribute__((address_space(1))) void*)(uintptr_t)(g),
        (__attribute__((address_space(3))) void*)(uintptr_t)(l), 16, 0, 0);
}

__device__ __forceinline__ float grpmax16(float v) {
    v = fmaxf(v, __shfl_xor(v, 1));
    v = fmaxf(v, __shfl_xor(v, 2));
    v = fmaxf(v, __shfl_xor(v, 4));
    v = fmaxf(v, __shfl_xor(v, 8));
    return v;
}
__device__ __forceinline__ float grpsum16(float v) {
    v += __shfl_xor(v, 1);
    v += __shfl_xor(v, 2);
    v += __shfl_xor(v, 4);
    v += __shfl_xor(v, 8);
    return v;
}

// ---------------- fp32 -> bf16 conversion (vectorized, grid-stride) ----------------
__global__ void cvt_f32_bf16(const float* __restrict__ src,
                             unsigned short* __restrict__ dst, int n4) {
    int i = blockIdx.x * blockDim.x + threadIdx.x;
    int stride = gridDim.x * blockDim.x;
    for (; i < n4; i += stride) {
        float4 v = ((const float4*)src)[i];
        ushort4 o;
        o.x = f2bf(v.x); o.y = f2bf(v.y); o.z = f2bf(v.z); o.w = f2bf(v.w);
        ((ushort4*)dst)[i] = o;
    }
}

// ---------------- GEMM: C[M=4096][N=1024] = A[M][K=1024] * W[N][K]^T ----------------
// EPI: 0 = Q store (scale 1/8, [B,H,S,DH] bf16)
//      1 = K store ([B,H,S,DH] bf16)
//      2 = V store transposed ([B,H,DH,S] bf16)
//      3 = fp32 out + bias
template <int EPI>
__global__ __launch_bounds__(256, 2)
void gemm_bt(const unsigned short* __restrict__ A,
             const unsigned short* __restrict__ Bw,
             void* __restrict__ out,
             const float* __restrict__ bias) {
    constexpr int M = 4096, N = 1024, K = 1024;
    constexpr int BM = 128, BN = 128, BK = 32;
    __shared__ __align__(16) unsigned short As[BM * BK];
    __shared__ __align__(16) unsigned short Bs[BN * BK];

    const int tid = threadIdx.x;
    const int l   = tid & 63;
    const int w   = tid >> 6;
    const int l15 = l & 15;
    const int lg  = l >> 4;
    const int bn  = blockIdx.x & 7;          // N/BN = 8
    const int bm  = blockIdx.x >> 3;
    const int wr  = w >> 1, wc = w & 1;

    f32x4 acc[4][4];
#pragma unroll
    for (int i = 0; i < 4; ++i)
#pragma unroll
        for (int j = 0; j < 4; ++j) acc[i][j] = (f32x4){0.f, 0.f, 0.f, 0.f};

    const int srow = tid >> 2;               // 4 threads / 32-elem row
    const int scol = (tid & 3) * 8;

    for (int kt = 0; kt < K / BK; ++kt) {
        const int kofs = kt * BK + scol;
        gload16(A  + (size_t)(bm * BM + srow) * K + kofs,       (char*)As + tid * 16);
        gload16(A  + (size_t)(bm * BM + srow + 64) * K + kofs,  (char*)As + 4096 + tid * 16);
        gload16(Bw + (size_t)(bn * BN + srow) * K + kofs,       (char*)Bs + tid * 16);
        gload16(Bw + (size_t)(bn * BN + srow + 64) * K + kofs,  (char*)Bs + 4096 + tid * 16);
        asm volatile("s_waitcnt vmcnt(0)" ::: "memory");
        __syncthreads();

        bf16x8 af[4], bf[4];
#pragma unroll
        for (int i = 0; i < 4; ++i)
            af[i] = *(const bf16x8*)&As[(wr * 64 + i * 16 + l15) * BK + 8 * lg];
#pragma unroll
        for (int j = 0; j < 4; ++j)
            bf[j] = *(const bf16x8*)&Bs[(wc * 64 + j * 16 + l15) * BK + 8 * lg];
#pragma unroll
        for (int i = 0; i < 4; ++i)
#pragma unroll
            for (int j = 0; j < 4; ++j)
                acc[i][j] = __builtin_amdgcn_mfma_f32_16x16x32_bf16(af[i], bf[j], acc[i][j], 0, 0, 0);
        __syncthreads();
    }

    // Epilogue: D[m][n] -> lane holds col n=l15(+16j), rows m=4*lg+r (+16i)
#pragma unroll
    for (int i = 0; i < 4; ++i)
#pragma unroll
        for (int j = 0; j < 4; ++j)
#pragma unroll
            for (int r = 0; r < 4; ++r) {
                int m = bm * BM + wr * 64 + i * 16 + 4 * lg + r;
                int n = bn * BN + wc * 64 + j * 16 + l15;
                float v = acc[i][j][r];
                if constexpr (EPI == 0) {
                    int bb = m >> 11, s = m & 2047, hh = n >> 6, dh = n & 63;
                    ((unsigned short*)out)[(((size_t)bb * H_ + hh) * S_ + s) * DH_ + dh] = f2bf(v * 0.125f);
                } else if constexpr (EPI == 1) {
                    int bb = m >> 11, s = m & 2047, hh = n >> 6, dh = n & 63;
                    ((unsigned short*)out)[(((size_t)bb * H_ + hh) * S_ + s) * DH_ + dh] = f2bf(v);
                } else if constexpr (EPI == 2) {
                    int bb = m >> 11, s = m & 2047, hh = n >> 6, dh = n & 63;
                    ((unsigned short*)out)[(((size_t)bb * H_ + hh) * DH_ + dh) * S_ + s] = f2bf(v);
                } else {
                    ((float*)out)[(size_t)m * N + n] = v + bias[n];
                }
            }
}

// ---------------- causal flash attention ----------------
// Qh,Kh: [B,H,S,DH] bf16 (Q pre-scaled by 1/8);  Vt: [B,H,DH,S] bf16
// Ows: [B,S,D] bf16
#define QBLK 64
#define KVBLK 64
#define KPAD 72

__global__ __launch_bounds__(256, 2)
void attn_causal(const unsigned short* __restrict__ Qh,
                 const unsigned short* __restrict__ Kh,
                 const unsigned short* __restrict__ Vt,
                 unsigned short* __restrict__ Ows) {
    __shared__ __align__(16) unsigned short K_lds[KVBLK * KPAD];
    __shared__ __align__(16) unsigned short V_lds[DH_ * KPAD];     // [dh][kv]
    __shared__ __align__(16) unsigned short P_lds[4 * 16 * KPAD];  // per-wave [16][KPAD]

    const int tid = threadIdx.x;
    const int l   = tid & 63;
    const int w   = tid >> 6;
    const int l15 = l & 15;
    const int lg  = l >> 4;
    const int qt  = blockIdx.x;      // q tile
    const int bh  = blockIdx.y;      // b*H + h
    const int b   = bh >> 4;
    const int h   = bh & 15;

    const unsigned short* Qbase = Qh + ((size_t)bh * S_ + qt * QBLK) * DH_;
    const unsigned short* Kbase = Kh + (size_t)bh * S_ * DH_;
    const unsigned short* Vbase = Vt + (size_t)bh * DH_ * S_;

    // Q A-fragments: rows w*16 + l15, k = 8*lg + j (+32)
    const int qrow = w * 16 + l15;
    bf16x8 qf0 = *(const bf16x8*)(Qbase + qrow * DH_ + 8 * lg);
    bf16x8 qf1 = *(const bf16x8*)(Qbase + qrow * DH_ + 32 + 8 * lg);

    f32x4 acc_o[4];
#pragma unroll
    for (int nd = 0; nd < 4; ++nd) acc_o[nd] = (f32x4){0.f, 0.f, 0.f, 0.f};
    float mrow[4], lrow[4];
#pragma unroll
    for (int r = 0; r < 4; ++r) { mrow[r] = -1e30f; lrow[r] = 0.f; }

    unsigned short* Pw = &P_lds[w * 16 * KPAD];

    const int ntiles = qt + 1;
    for (int t = 0; t < ntiles; ++t) {
        __syncthreads();   // previous tile's LDS reads complete
        // stage K [kv][dh] and Vt [dh][kv] tiles (coalesced, reg-staged, padded rows)
#pragma unroll
        for (int p = 0; p < 2; ++p) {
            int idx = p * 256 + tid;
            int row = idx >> 3;
            int col = (idx & 7) * 8;
            bf16x8 kv = *(const bf16x8*)(Kbase + (size_t)(t * KVBLK + row) * DH_ + col);
            *(bf16x8*)&K_lds[row * KPAD + col] = kv;
            bf16x8 vv = *(const bf16x8*)(Vbase + (size_t)row * S_ + t * KVBLK + col);
            *(bf16x8*)&V_lds[row * KPAD + col] = vv;
        }
        __syncthreads();

        // S = Q K^T  (16 q-rows x 64 kv)
        f32x4 sacc[4];
#pragma unroll
        for (int ng = 0; ng < 4; ++ng) sacc[ng] = (f32x4){0.f, 0.f, 0.f, 0.f};
#pragma unroll
        for (int ng = 0; ng < 4; ++ng) {
            bf16x8 kf0 = *(const bf16x8*)&K_lds[(ng * 16 + l15) * KPAD + 8 * lg];
            bf16x8 kf1 = *(const bf16x8*)&K_lds[(ng * 16 + l15) * KPAD + 32 + 8 * lg];
            sacc[ng] = __builtin_amdgcn_mfma_f32_16x16x32_bf16(qf0, kf0, sacc[ng], 0, 0, 0);
            sacc[ng] = __builtin_amdgcn_mfma_f32_16x16x32_bf16(qf1, kf1, sacc[ng], 0, 0, 0);
        }

        if (t == qt) {  // diagonal tile: causal mask (local index compare valid)
#pragma unroll
            for (int ng = 0; ng < 4; ++ng) {
                int kvloc = ng * 16 + l15;
#pragma unroll
                for (int r = 0; r < 4; ++r) {
                    int qloc = w * 16 + 4 * lg + r;
                    if (kvloc > qloc) sacc[ng][r] = -1e30f;
                }
            }
        }

        // online softmax (rows m=4*lg+r live in 16-lane groups)
        float mnew[4], scale[4], rsum[4];
#pragma unroll
        for (int r = 0; r < 4; ++r) {
            float v = fmaxf(fmaxf(sacc[0][r], sacc[1][r]), fmaxf(sacc[2][r], sacc[3][r]));
            v = grpmax16(v);
            mnew[r]  = fmaxf(mrow[r], v);
            scale[r] = __expf(mrow[r] - mnew[r]);
            mrow[r]  = mnew[r];
            rsum[r]  = 0.f;
        }
#pragma unroll
        for (int ng = 0; ng < 4; ++ng)
#pragma unroll
            for (int r = 0; r < 4; ++r) {
                float pv = __expf(sacc[ng][r] - mnew[r]);
                sacc[ng][r] = pv;
                rsum[r] += pv;
            }
#pragma unroll
        for (int r = 0; r < 4; ++r) {
            lrow[r] = lrow[r] * scale[r] + grpsum16(rsum[r]);
        }
#pragma unroll
        for (int nd = 0; nd < 4; ++nd)
#pragma unroll
            for (int r = 0; r < 4; ++r) acc_o[nd][r] *= scale[r];

        // P -> per-wave LDS (bf16), wave-internal ordering only
#pragma unroll
        for (int ng = 0; ng < 4; ++ng)
#pragma unroll
            for (int r = 0; r < 4; ++r)
                Pw[(4 * lg + r) * KPAD + ng * 16 + l15] = f2bf(sacc[ng][r]);

        // O += P V   (A = P[16 x 32kc] from P_lds, B = V[kc][dh] from Vt tile)
#pragma unroll
        for (int kc = 0; kc < 2; ++kc) {
            bf16x8 pf = *(const bf16x8*)&Pw[l15 * KPAD + kc * 32 + 8 * lg];
#pragma unroll
            for (int nd = 0; nd < 4; ++nd) {
                bf16x8 vf = *(const bf16x8*)&V_lds[(nd * 16 + l15) * KPAD + kc * 32 + 8 * lg];
                acc_o[nd] = __builtin_amdgcn_mfma_f32_16x16x32_bf16(pf, vf, acc_o[nd], 0, 0, 0);
            }
        }
    }

    // epilogue: O/l -> Ows[b][s][h*64+dh]
#pragma unroll
    for (int nd = 0; nd < 4; ++nd)
#pragma unroll
        for (int r = 0; r < 4; ++r) {
            float val = acc_o[nd][r] / lrow[r];
            int qloc = w * 16 + 4 * lg + r;
            Ows[((size_t)b * S_ + qt * QBLK + qloc) * D_ + h * DH_ + nd * 16 + l15] = f2bf(val);
        }
}

// ---------------- launch ----------------
extern "C" void kernel_launch(void* const* d_in, const int* in_sizes, int n_in,
                              void* d_out, int out_size, void* d_ws, size_t ws_size,
                              hipStream_t stream) {
    const float* q    = (const float*)d_in[0];
    const float* k    = (const float*)d_in[1];
    const float* v    = (const float*)d_in[2];
    // d_in[3] = causal tril mask (computed analytically)
    const float* Wq   = (const float*)d_in[4];
    const float* Wk   = (const float*)d_in[5];
    const float* Wv   = (const float*)d_in[6];
    const float* Wo   = (const float*)d_in[7];
    const float* bo   = (const float*)d_in[8];

    unsigned char* ws = (unsigned char*)d_ws;
    const size_t MB = 1u << 20;
    unsigned short* q_bf  = (unsigned short*)(ws + 0 * MB);
    unsigned short* k_bf  = (unsigned short*)(ws + 8 * MB);
    unsigned short* v_bf  = (unsigned short*)(ws + 16 * MB);
    unsigned short* wq_bf = (unsigned short*)(ws + 24 * MB);
    unsigned short* wk_bf = (unsigned short*)(ws + 26 * MB);
    unsigned short* wv_bf = (unsigned short*)(ws + 28 * MB);
    unsigned short* wo_bf = (unsigned short*)(ws + 30 * MB);
    unsigned short* Qh    = (unsigned short*)(ws + 32 * MB);
    unsigned short* Kh    = (unsigned short*)(ws + 40 * MB);
    unsigned short* Vt    = (unsigned short*)(ws + 48 * MB);
    unsigned short* Ows   = (unsigned short*)(ws + 56 * MB);

    const int nQKV4 = (B_ * S_ * D_) / 4;   // 1048576
    const int nW4   = (D_ * D_) / 4;        // 262144

    cvt_f32_bf16<<<1024, 256, 0, stream>>>(q,  q_bf,  nQKV4);
    cvt_f32_bf16<<<1024, 256, 0, stream>>>(k,  k_bf,  nQKV4);
    cvt_f32_bf16<<<1024, 256, 0, stream>>>(v,  v_bf,  nQKV4);
    cvt_f32_bf16<<<512,  256, 0, stream>>>(Wq, wq_bf, nW4);
    cvt_f32_bf16<<<512,  256, 0, stream>>>(Wk, wk_bf, nW4);
    cvt_f32_bf16<<<512,  256, 0, stream>>>(Wv, wv_bf, nW4);
    cvt_f32_bf16<<<512,  256, 0, stream>>>(Wo, wo_bf, nW4);

    gemm_bt<0><<<256, 256, 0, stream>>>(q_bf, wq_bf, Qh, nullptr);
    gemm_bt<1><<<256, 256, 0, stream>>>(k_bf, wk_bf, Kh, nullptr);
    gemm_bt<2><<<256, 256, 0, stream>>>(v_bf, wv_bf, Vt, nullptr);

    attn_causal<<<dim3(S_ / QBLK, B_ * H_), 256, 0, stream>>>(Qh, Kh, Vt, Ows);

    gemm_bt<3><<<256, 256, 0, stream>>>(Ows, wo_bf, d_out, bo);
}

// Round 10
// 193.100 us; speedup vs baseline: 1.2638x; 1.2638x over previous
//
#include <hip/hip_runtime.h>
#include <hip/hip_bf16.h>
#include <stdint.h>

#define B_  2
#define S_  2048
#define D_  1024
#define H_  16
#define DH_ 64

typedef __attribute__((ext_vector_type(8))) short  bf16x8;
typedef __attribute__((ext_vector_type(4))) float  f32x4;
typedef unsigned short u16;

__device__ __forceinline__ u16 f2bf(float f) {
    unsigned u = __float_as_uint(f);
    u += 0x7FFF + ((u >> 16) & 1);            // RNE
    return (u16)(u >> 16);
}

__device__ __forceinline__ void gload16(const void* g, void* l) {
    __builtin_amdgcn_global_load_lds(
        (__attribute__((address_space(1))) void*)(uintptr_t)(g),
        (__attribute__((address_space(3))) void*)(uintptr_t)(l), 16, 0, 0);
}

__device__ __forceinline__ float grpmax16(float v) {
    v = fmaxf(v, __shfl_xor(v, 1));
    v = fmaxf(v, __shfl_xor(v, 2));
    v = fmaxf(v, __shfl_xor(v, 4));
    v = fmaxf(v, __shfl_xor(v, 8));
    return v;
}
__device__ __forceinline__ float grpsum16(float v) {
    v += __shfl_xor(v, 1);
    v += __shfl_xor(v, 2);
    v += __shfl_xor(v, 4);
    v += __shfl_xor(v, 8);
    return v;
}

// ---------------- fused fp32 -> bf16 conversion for all 7 tensors ----------------
__global__ void cvt_all(const float* __restrict__ q, const float* __restrict__ k,
                        const float* __restrict__ v, const float* __restrict__ wq,
                        const float* __restrict__ wk, const float* __restrict__ wv,
                        const float* __restrict__ wo,
                        u16* qb, u16* kb, u16* vb, u16* wqb, u16* wkb, u16* wvb, u16* wob) {
    const int NQ = (B_ * S_ * D_) / 4;   // 1<<20
    const int NW = (D_ * D_) / 4;        // 1<<18
    const int total = 3 * NQ + 4 * NW;   // 4194304
    int i = blockIdx.x * 256 + threadIdx.x;
    const int stride = gridDim.x * 256;
    for (; i < total; i += stride) {
        const float* s; u16* d; int off;
        if (i < 3 * NQ) {
            int wh = i >> 20; off = i & (NQ - 1);
            s = wh == 0 ? q : (wh == 1 ? k : v);
            d = wh == 0 ? qb : (wh == 1 ? kb : vb);
        } else {
            int j = i - 3 * NQ;
            int wh = j >> 18; off = j & (NW - 1);
            s = wh == 0 ? wq : (wh == 1 ? wk : (wh == 2 ? wv : wo));
            d = wh == 0 ? wqb : (wh == 1 ? wkb : (wh == 2 ? wvb : wob));
        }
        float4 x = ((const float4*)s)[off];
        ushort4 o;
        o.x = f2bf(x.x); o.y = f2bf(x.y); o.z = f2bf(x.z); o.w = f2bf(x.w);
        ((ushort4*)d)[off] = o;
    }
}

// ---------------- GEMM core: C[128x128] tile of A[M][1024] * W[1024][1024]^T ----------------
__device__ __forceinline__ void gemm_core(const u16* __restrict__ A, const u16* __restrict__ Bw,
                                          u16* As, u16* Bs, int bm, int bn, f32x4 acc[4][4]) {
    constexpr int K = 1024, BK = 32;
    const int tid = threadIdx.x;
    const int l15 = tid & 15;
    const int lg  = (tid >> 4) & 3;
    const int w   = tid >> 6;
    const int wr  = w >> 1, wc = w & 1;
    const int srow = tid >> 2;
    const int scol = (tid & 3) * 8;

    for (int kt = 0; kt < K / BK; ++kt) {
        const int kofs = kt * BK + scol;
        gload16(A  + (size_t)(bm * 128 + srow) * K + kofs,       (char*)As + tid * 16);
        gload16(A  + (size_t)(bm * 128 + srow + 64) * K + kofs,  (char*)As + 4096 + tid * 16);
        gload16(Bw + (size_t)(bn * 128 + srow) * K + kofs,       (char*)Bs + tid * 16);
        gload16(Bw + (size_t)(bn * 128 + srow + 64) * K + kofs,  (char*)Bs + 4096 + tid * 16);
        asm volatile("s_waitcnt vmcnt(0)" ::: "memory");
        __syncthreads();

        bf16x8 af[4], bfr[4];
#pragma unroll
        for (int i = 0; i < 4; ++i)
            af[i] = *(const bf16x8*)&As[(wr * 64 + i * 16 + l15) * BK + 8 * lg];
#pragma unroll
        for (int j = 0; j < 4; ++j)
            bfr[j] = *(const bf16x8*)&Bs[(wc * 64 + j * 16 + l15) * BK + 8 * lg];
#pragma unroll
        for (int i = 0; i < 4; ++i)
#pragma unroll
            for (int j = 0; j < 4; ++j)
                acc[i][j] = __builtin_amdgcn_mfma_f32_16x16x32_bf16(af[i], bfr[j], acc[i][j], 0, 0, 0);
        __syncthreads();
    }
}

// fused Q/K/V projection: grid 768 blocks (z = id>>8 selects which)
__global__ __launch_bounds__(256, 2)
void gemm_qkv(const u16* __restrict__ qb, const u16* __restrict__ kb, const u16* __restrict__ vb,
              const u16* __restrict__ wqb, const u16* __restrict__ wkb, const u16* __restrict__ wvb,
              u16* __restrict__ Qh, u16* __restrict__ Kh, u16* __restrict__ Vt) {
    __shared__ __align__(16) u16 As[128 * 32];
    __shared__ __align__(16) u16 Bs[128 * 32];
    int id = ((blockIdx.x & 7) * 96) + (blockIdx.x >> 3);   // XCD swizzle (768%8==0)
    const int z  = id >> 8;
    const int rm = id & 255;
    const int bn = rm & 7;
    const int bm = rm >> 3;
    const u16* A  = z == 0 ? qb  : (z == 1 ? kb  : vb);
    const u16* Bw = z == 0 ? wqb : (z == 1 ? wkb : wvb);

    f32x4 acc[4][4];
#pragma unroll
    for (int i = 0; i < 4; ++i)
#pragma unroll
        for (int j = 0; j < 4; ++j) acc[i][j] = (f32x4){0.f, 0.f, 0.f, 0.f};

    gemm_core(A, Bw, As, Bs, bm, bn, acc);

    const int tid = threadIdx.x;
    const int l15 = tid & 15, lg = (tid >> 4) & 3, w = tid >> 6;
    const int wr = w >> 1, wc = w & 1;
    const float QSCALE = 0.18033688011112042f;   // log2(e) / sqrt(64)

#pragma unroll
    for (int i = 0; i < 4; ++i)
#pragma unroll
        for (int j = 0; j < 4; ++j) {
            int m0 = bm * 128 + wr * 64 + i * 16 + 4 * lg;
            int n  = bn * 128 + wc * 64 + j * 16 + l15;
            int bb = m0 >> 11, s0 = m0 & 2047, hh = n >> 6, dh = n & 63;
            if (z == 2) {            // V transposed: [B,H,DH,S], vectorize over 4 rows (s)
                ushort4 pk;
                pk.x = f2bf(acc[i][j][0]); pk.y = f2bf(acc[i][j][1]);
                pk.z = f2bf(acc[i][j][2]); pk.w = f2bf(acc[i][j][3]);
                *(ushort4*)&Vt[(((size_t)bb * H_ + hh) * DH_ + dh) * S_ + s0] = pk;
            } else {
                u16* dst = (z == 0) ? Qh : Kh;
                float sc = (z == 0) ? QSCALE : 1.0f;
#pragma unroll
                for (int r = 0; r < 4; ++r)
                    dst[(((size_t)bb * H_ + hh) * S_ + s0 + r) * DH_ + dh] = f2bf(acc[i][j][r] * sc);
            }
        }
}

// output projection: fp32 out + bias
__global__ __launch_bounds__(256, 2)
void gemm_o(const u16* __restrict__ A, const u16* __restrict__ Bw,
            float* __restrict__ out, const float* __restrict__ bias) {
    __shared__ __align__(16) u16 As[128 * 32];
    __shared__ __align__(16) u16 Bs[128 * 32];
    int id = ((blockIdx.x & 7) * 32) + (blockIdx.x >> 3);   // XCD swizzle (256%8==0)
    const int bn = id & 7;
    const int bm = id >> 3;

    f32x4 acc[4][4];
#pragma unroll
    for (int i = 0; i < 4; ++i)
#pragma unroll
        for (int j = 0; j < 4; ++j) acc[i][j] = (f32x4){0.f, 0.f, 0.f, 0.f};

    gemm_core(A, Bw, As, Bs, bm, bn, acc);

    const int tid = threadIdx.x;
    const int l15 = tid & 15, lg = (tid >> 4) & 3, w = tid >> 6;
    const int wr = w >> 1, wc = w & 1;
#pragma unroll
    for (int i = 0; i < 4; ++i)
#pragma unroll
        for (int j = 0; j < 4; ++j) {
            int n = bn * 128 + wc * 64 + j * 16 + l15;
            float bv = bias[n];
#pragma unroll
            for (int r = 0; r < 4; ++r) {
                int m = bm * 128 + wr * 64 + i * 16 + 4 * lg + r;
                out[(size_t)m * 1024 + n] = acc[i][j][r] + bv;
            }
        }
}

// ---------------- causal flash attention, barrier-free direct-load ----------------
// Qh,Kh: [B,H,S,DH] bf16 (Q pre-scaled by log2e/8); Vt: [B,H,DH,S] bf16; Ows: [B,S,D] bf16
// Wave = one 16-row q-tile; wave handles the pair {a, 127-a} for causal load balance.
#define PPAD 80

__global__ __launch_bounds__(256)
void attn_flash(const u16* __restrict__ Qh, const u16* __restrict__ Kh,
                const u16* __restrict__ Vt, u16* __restrict__ Ows) {
    __shared__ __align__(16) u16 P_lds[4][16 * PPAD];
    const int tid = threadIdx.x;
    const int l   = tid & 63;
    const int w   = tid >> 6;
    const int l15 = l & 15;
    const int lg  = l >> 4;

    int id = ((blockIdx.x & 7) << 6) + (blockIdx.x >> 3);   // XCD swizzle: 4 heads per XCD
    const int bh = id >> 4;          // b*H + h
    const int jj = id & 15;
    const int b  = bh >> 4;
    const int h  = bh & 15;
    const int a  = jj * 4 + w;       // 0..63  (q16-tile pair index)

    const u16* Kbase = Kh + (size_t)bh * S_ * DH_;
    const u16* Vbase = Vt + (size_t)bh * DH_ * S_;
    u16* Pw = P_lds[w];

    for (int pass = 0; pass < 2; ++pass) {
        const int qt = pass ? (127 - a) : a;           // q16-tile index
        const u16* Qbase = Qh + ((size_t)bh * S_ + qt * 16) * DH_;
        bf16x8 qf0 = *(const bf16x8*)(Qbase + l15 * DH_ + 8 * lg);
        bf16x8 qf1 = *(const bf16x8*)(Qbase + l15 * DH_ + 32 + 8 * lg);

        f32x4 acc[4];
#pragma unroll
        for (int nd = 0; nd < 4; ++nd) acc[nd] = (f32x4){0.f, 0.f, 0.f, 0.f};
        float mr[4], lr[4];
#pragma unroll
        for (int r = 0; r < 4; ++r) { mr[r] = -1e30f; lr[r] = 0.f; }

        const int ntiles = (qt >> 2) + 1;              // kv tiles of 64
        for (int t = 0; t < ntiles; ++t) {
            const u16* Kt = Kbase + (size_t)t * 64 * DH_;
            // K fragments (B-operand: row = kv, k = dh)
            bf16x8 kf0[4], kf1[4];
#pragma unroll
            for (int ng = 0; ng < 4; ++ng) {
                kf0[ng] = *(const bf16x8*)(Kt + (ng * 16 + l15) * DH_ + 8 * lg);
                kf1[ng] = *(const bf16x8*)(Kt + (ng * 16 + l15) * DH_ + 32 + 8 * lg);
            }
            // V fragments prefetch (B-operand of PV: row = dh, k = kv)
            bf16x8 vf[2][4];
#pragma unroll
            for (int kc = 0; kc < 2; ++kc)
#pragma unroll
                for (int nd = 0; nd < 4; ++nd)
                    vf[kc][nd] = *(const bf16x8*)(Vbase + (size_t)(nd * 16 + l15) * S_ +
                                                  t * 64 + kc * 32 + 8 * lg);

            f32x4 sacc[4];
#pragma unroll
            for (int ng = 0; ng < 4; ++ng) {
                sacc[ng] = (f32x4){0.f, 0.f, 0.f, 0.f};
                sacc[ng] = __builtin_amdgcn_mfma_f32_16x16x32_bf16(qf0, kf0[ng], sacc[ng], 0, 0, 0);
                sacc[ng] = __builtin_amdgcn_mfma_f32_16x16x32_bf16(qf1, kf1[ng], sacc[ng], 0, 0, 0);
            }

            if (t == ntiles - 1) {                     // causal mask on final tile
                const int qb0 = qt * 16 + 4 * lg;
#pragma unroll
                for (int ng = 0; ng < 4; ++ng) {
                    int kvg = t * 64 + ng * 16 + l15;
#pragma unroll
                    for (int r = 0; r < 4; ++r)
                        if (kvg > qb0 + r) sacc[ng][r] = -1e30f;
                }
            }

            // online softmax (base-2 domain; log2e folded into Q scale)
            float mnew[4], rs[4];
#pragma unroll
            for (int r = 0; r < 4; ++r) {
                float v = fmaxf(fmaxf(sacc[0][r], sacc[1][r]), fmaxf(sacc[2][r], sacc[3][r]));
                v = grpmax16(v);
                mnew[r] = fmaxf(mr[r], v);
                float sc = exp2f(mr[r] - mnew[r]);
                mr[r] = mnew[r];
                lr[r] *= sc;
                acc[0][r] *= sc; acc[1][r] *= sc; acc[2][r] *= sc; acc[3][r] *= sc;
                rs[r] = 0.f;
            }
#pragma unroll
            for (int ng = 0; ng < 4; ++ng)
#pragma unroll
                for (int r = 0; r < 4; ++r) {
                    float pv = exp2f(sacc[ng][r] - mnew[r]);
                    sacc[ng][r] = pv;
                    rs[r] += pv;
                }
#pragma unroll
            for (int r = 0; r < 4; ++r) lr[r] += grpsum16(rs[r]);

            // P C-layout -> A-layout via per-wave LDS (no barrier; wave-coherent)
#pragma unroll
            for (int ng = 0; ng < 4; ++ng)
#pragma unroll
                for (int r = 0; r < 4; ++r)
                    Pw[(4 * lg + r) * PPAD + ng * 16 + l15] = f2bf(sacc[ng][r]);

#pragma unroll
            for (int kc = 0; kc < 2; ++kc) {
                bf16x8 pf = *(const bf16x8*)&Pw[l15 * PPAD + kc * 32 + 8 * lg];
#pragma unroll
                for (int nd = 0; nd < 4; ++nd)
                    acc[nd] = __builtin_amdgcn_mfma_f32_16x16x32_bf16(pf, vf[kc][nd], acc[nd], 0, 0, 0);
            }
        }

        // epilogue
#pragma unroll
        for (int r = 0; r < 4; ++r) {
            float inv = 1.0f / lr[r];
            int srow = qt * 16 + 4 * lg + r;
#pragma unroll
            for (int nd = 0; nd < 4; ++nd)
                Ows[((size_t)b * S_ + srow) * D_ + h * DH_ + nd * 16 + l15] =
                    f2bf(acc[nd][r] * inv);
        }
    }
}

// ---------------- launch ----------------
extern "C" void kernel_launch(void* const* d_in, const int* in_sizes, int n_in,
                              void* d_out, int out_size, void* d_ws, size_t ws_size,
                              hipStream_t stream) {
    const float* q  = (const float*)d_in[0];
    const float* k  = (const float*)d_in[1];
    const float* v  = (const float*)d_in[2];
    // d_in[3] = causal tril mask (computed analytically)
    const float* Wq = (const float*)d_in[4];
    const float* Wk = (const float*)d_in[5];
    const float* Wv = (const float*)d_in[6];
    const float* Wo = (const float*)d_in[7];
    const float* bo = (const float*)d_in[8];

    unsigned char* ws = (unsigned char*)d_ws;
    const size_t MB = 1u << 20;
    u16* q_bf  = (u16*)(ws + 0 * MB);
    u16* k_bf  = (u16*)(ws + 8 * MB);
    u16* v_bf  = (u16*)(ws + 16 * MB);
    u16* wq_bf = (u16*)(ws + 24 * MB);
    u16* wk_bf = (u16*)(ws + 26 * MB);
    u16* wv_bf = (u16*)(ws + 28 * MB);
    u16* wo_bf = (u16*)(ws + 30 * MB);
    u16* Qh    = (u16*)(ws + 32 * MB);
    u16* Kh    = (u16*)(ws + 40 * MB);
    u16* Vt    = (u16*)(ws + 48 * MB);
    u16* Ows   = (u16*)(ws + 56 * MB);

    cvt_all<<<2048, 256, 0, stream>>>(q, k, v, Wq, Wk, Wv, Wo,
                                      q_bf, k_bf, v_bf, wq_bf, wk_bf, wv_bf, wo_bf);
    gemm_qkv<<<768, 256, 0, stream>>>(q_bf, k_bf, v_bf, wq_bf, wk_bf, wv_bf, Qh, Kh, Vt);
    attn_flash<<<512, 256, 0, stream>>>(Qh, Kh, Vt, Ows);
    gemm_o<<<256, 256, 0, stream>>>(Ows, wo_bf, (float*)d_out, bo);
}